// Round 8
// baseline (412.536 us; speedup 1.0000x reference)
//
#include <hip/hip_runtime.h>
#include <hip/hip_bf16.h>

#define DIM 128
typedef unsigned int u32;

typedef __attribute__((ext_vector_type(8))) short bf16x8;   // 8 bf16 (4 VGPRs)
typedef __attribute__((ext_vector_type(4))) float f32x4;    // MFMA accumulator
typedef __attribute__((ext_vector_type(2))) float f32x2;

// bf16x2 pack/unpack: low ushort = even feature, high = odd feature.
__device__ __forceinline__ u32 pack_bf16x2(float a, float b) {
    u32 ua = __float_as_uint(a), ub = __float_as_uint(b);
    ua = (ua + 0x7FFFu + ((ua >> 16) & 1u)) >> 16;        // RNE
    ub = (ub + 0x7FFFu + ((ub >> 16) & 1u)) >> 16;
    return ua | (ub << 16);
}
__device__ __forceinline__ float2 unpack_bf16x2(u32 h) {
    return make_float2(__uint_as_float(h << 16), __uint_as_float(h & 0xFFFF0000u));
}

// ======================= fp8 e4m3 helpers =======================
// Gather tables are fp8, pre-scaled by 16 (consumers descale via dinv/16).
// R4-R7 evidence: gather time tracks per-wave ITERATION count (divergence =
// max degree over the wave's node-groups), not bytes/lines/instructions.
// This round: degree-sorted perm -> waves process equal-degree nodes.
#if __has_builtin(__builtin_amdgcn_cvt_pk_f32_fp8) && __has_builtin(__builtin_amdgcn_cvt_pk_fp8_f32)
#define FP8_HW 1
#endif

__device__ __forceinline__ void dec4(float* d, u32 w) {
#ifdef FP8_HW
    f32x2 a = __builtin_amdgcn_cvt_pk_f32_fp8((int)w, false);
    f32x2 b = __builtin_amdgcn_cvt_pk_f32_fp8((int)w, true);
    d[0] = a.x; d[1] = a.y; d[2] = b.x; d[3] = b.y;
#else
    #pragma unroll
    for (int i = 0; i < 4; ++i) {
        u32 v = (w >> (8 * i)) & 0xFFu;
        u32 s = v >> 7, e = (v >> 3) & 15u, m = v & 7u;
        float nv = __uint_as_float((s << 31) | ((e + 120u) << 23) | (m << 20));
        float sv = (s ? -1.f : 1.f) * (float)m * 0.001953125f;   // m * 2^-9
        d[i] = e ? nv : sv;
    }
#endif
}

#ifndef FP8_HW
__device__ __forceinline__ u32 enc_byte(float f) {   // software RNE e4m3
    u32 s = __float_as_uint(f) >> 31;
    float af = fminf(fabsf(f), 448.f);
    u32 b;
    if (af >= 0.015625f) {                       // normal (>= 2^-6)
        u32 m = __float_as_uint(af);
        m = m + 0x0007FFFFu + ((m >> 20) & 1u);  // RNE at bit 20
        u32 fe = (m >> 23) - 120u;
        if (fe > 15u) b = (15u << 3) | 6u;       // saturate to 448
        else          b = (fe << 3) | ((m >> 20) & 7u);
    } else {
        b = (u32)rintf(af * 512.f);              // subnormal quantum 2^-9
    }
    return b | (s << 7);
}
#endif

// HI must be a compile-time constant (ICE requirement of the builtin).
template<bool HI>
__device__ __forceinline__ u32 enc_pair(float a, float b, u32 old) {
#ifdef FP8_HW
    return (u32)__builtin_amdgcn_cvt_pk_fp8_f32(a, b, (int)old, HI);
#else
    u32 p = enc_byte(a) | (enc_byte(b) << 8);
    return HI ? ((old & 0x0000FFFFu) | (p << 16)) : ((old & 0xFFFF0000u) | p);
#endif
}

__device__ __forceinline__ void addrow16(float* acc, uint4 r) {
    float d[4];
    dec4(d, r.x);
    acc[0]  += d[0]; acc[1]  += d[1]; acc[2]  += d[2]; acc[3]  += d[3];
    dec4(d, r.y);
    acc[4]  += d[0]; acc[5]  += d[1]; acc[6]  += d[2]; acc[7]  += d[3];
    dec4(d, r.z);
    acc[8]  += d[0]; acc[9]  += d[1]; acc[10] += d[2]; acc[11] += d[3];
    dec4(d, r.w);
    acc[12] += d[0]; acc[13] += d[1]; acc[14] += d[2]; acc[15] += d[3];
}

// ======================= count + rank =======================
__global__ void count_rank(int* __restrict__ deg, const int* __restrict__ dst,
                           int* __restrict__ rank, int* __restrict__ total, int E,
                           int* __restrict__ hist)
{
    int e = blockIdx.x * blockDim.x + threadIdx.x;
    if (e == 0) *total = 0;
    if (e < 256) hist[e] = 0;            // degree histogram (read next kernel)
    if (e < E) rank[e] = atomicAdd(&deg[dst[e]], 1);
}

// ======================= CSR offsets =======================
// Buckets padded to x4; pad slots point at the zero row (index N).
// rng[i] = (start, padded end). Also builds the degree histogram.
__global__ __launch_bounds__(256) void alloc_offsets(
    const int* __restrict__ deg, int2* __restrict__ rng,
    float* __restrict__ dinv, int* __restrict__ total,
    int* __restrict__ csr, int N,
    float* __restrict__ sums, float* __restrict__ cnt, int G,
    u32* __restrict__ B0, u32* __restrict__ B1, int* __restrict__ hist)
{
    int i = blockIdx.x * blockDim.x + threadIdx.x;
    int lane = threadIdx.x & 63;
    if (i < G) { sums[i] = 0.f; cnt[i] = 0.f; }
    if (i < 32) {                          // zero row N of both fp8 tables
        B0[(size_t)N * 32 + i] = 0u;
        B1[(size_t)N * 32 + i] = 0u;
    }
    int d  = (i < N) ? deg[i] : 0;
    int d4 = (d + 3) & ~3;
    int pre = d4;
    #pragma unroll
    for (int off = 1; off < 64; off <<= 1) {
        int v = __shfl_up(pre, off, 64);
        if (lane >= off) pre += v;
    }
    int waveTot = __shfl(pre, 63, 64);
    int base = 0;
    if (lane == 63) base = atomicAdd(total, waveTot);
    base = __shfl(base, 63, 64);
    if (i < N) {
        int st = base + pre - d4;
        rng[i] = make_int2(st, st + d4);
        dinv[i]  = rsqrtf((float)(d + 1));   // +1 self-loop
        for (int p = d; p < d4; ++p)         // pads -> zero row
            csr[st + p] = N;
        atomicAdd(&hist[d < 255 ? d : 255], 1);
    }
}

// ============ degree-bucket exclusive scan (1 block) ============
__global__ __launch_bounds__(256) void scan_kernel(const int* __restrict__ hist,
                                                   int* __restrict__ cursor)
{
    __shared__ int tmp[256];
    int t = threadIdx.x;
    int h = hist[t];
    tmp[t] = h;
    __syncthreads();
    for (int off = 1; off < 256; off <<= 1) {
        int v = (t >= off) ? tmp[t - off] : 0;
        __syncthreads();
        tmp[t] += v;
        __syncthreads();
    }
    cursor[t] = tmp[t] - h;   // exclusive prefix = bucket base
}

// ======================= GEMM1 body (MFMA) =======================
// Y[node] = fp8(16 * dinv[node] * (X[node] @ W)), node-major 32 u32/row.
__device__ __forceinline__ void gemm_body0(
    const float* __restrict__ X, const float* __restrict__ W,
    const float* __restrict__ dinv, u32* __restrict__ Y, int N,
    int tile0, int tstride)
{
    __shared__ u32   Abuf[16][68];
    __shared__ float Dbuf[16][132];

    const int t    = threadIdx.x;
    const int grp  = t >> 4;
    const int gl   = t & 15;
    const int lane = t & 63;
    const int wv   = t >> 6;
    const int lrow = lane & 15;
    const int lhi  = lane >> 4;

    bf16x8 bfr[2][4];
    {
        const float* wp = W + (size_t)(lhi * 8) * DIM + wv * 32 + lrow;
        #pragma unroll
        for (int nt = 0; nt < 2; ++nt)
            #pragma unroll
            for (int kc = 0; kc < 4; ++kc) {
                const float* p = wp + (size_t)(kc * 32) * DIM + nt * 16;
                union { u32 u[4]; bf16x8 v; } tmp;
                #pragma unroll
                for (int e = 0; e < 4; ++e)
                    tmp.u[e] = pack_bf16x2(p[(size_t)(2 * e) * DIM],
                                           p[(size_t)(2 * e + 1) * DIM]);
                bfr[nt][kc] = tmp.v;
            }
    }

    const int ntiles = (N + 15) >> 4;
    for (int tile = tile0; tile < ntiles; tile += tstride) {
        const int node = tile * 16 + grp;
        const bool valid = node < N;

        float4 a0 = make_float4(0.f, 0.f, 0.f, 0.f);
        float4 a1 = make_float4(0.f, 0.f, 0.f, 0.f);
        if (valid) {
            a0 = *(const float4*)&X[(size_t)node * DIM + gl * 8];
            a1 = *(const float4*)&X[(size_t)node * DIM + gl * 8 + 4];
        }
        uint4 pk;
        pk.x = pack_bf16x2(a0.x, a0.y);
        pk.y = pack_bf16x2(a0.z, a0.w);
        pk.z = pack_bf16x2(a1.x, a1.y);
        pk.w = pack_bf16x2(a1.z, a1.w);
        *(uint4*)&Abuf[grp][gl * 4] = pk;
        __syncthreads();                                   // barrier A

        f32x4 c0 = {0.f, 0.f, 0.f, 0.f};
        f32x4 c1 = {0.f, 0.f, 0.f, 0.f};
        #pragma unroll
        for (int kc = 0; kc < 4; ++kc) {
            bf16x8 afr = *(const bf16x8*)&Abuf[lrow][kc * 16 + lhi * 4];
            c0 = __builtin_amdgcn_mfma_f32_16x16x32_bf16(afr, bfr[0][kc], c0, 0, 0, 0);
            c1 = __builtin_amdgcn_mfma_f32_16x16x32_bf16(afr, bfr[1][kc], c1, 0, 0, 0);
        }
        #pragma unroll
        for (int r = 0; r < 4; ++r) {
            Dbuf[lhi * 4 + r][wv * 32 + lrow]      = c0[r];
            Dbuf[lhi * 4 + r][wv * 32 + 16 + lrow] = c1[r];
        }
        __syncthreads();                                   // barrier B

        if (valid) {
            float dnp = 16.f * dinv[node];
            float4 o0 = *(const float4*)&Dbuf[grp][gl * 8];
            float4 o1 = *(const float4*)&Dbuf[grp][gl * 8 + 4];
            u32 lo = enc_pair<false>(dnp * o0.x, dnp * o0.y, 0u);
            lo     = enc_pair<true >(dnp * o0.z, dnp * o0.w, lo);
            u32 hi = enc_pair<false>(dnp * o1.x, dnp * o1.y, 0u);
            hi     = enc_pair<true >(dnp * o1.z, dnp * o1.w, hi);
            *(uint2*)&Y[(size_t)node * 32 + gl * 2] = make_uint2(lo, hi);
        }
    }
}

// Fused: [0,gblocks) MFMA gemm1; [gblocks,gblocks+eblocks) CSR edge scatter;
// the rest scatter nodes into the degree-sorted permutation.
__global__ __launch_bounds__(256) void scatter_gemm1(
    const float* __restrict__ x, const float* __restrict__ W1,
    const float* __restrict__ dinv, u32* __restrict__ Y, int N, int gblocks,
    const int* __restrict__ src, const int* __restrict__ dst,
    const int* __restrict__ rank, const int2* __restrict__ rng,
    int* __restrict__ csr, int E, int eblocks,
    const int* __restrict__ deg, int* __restrict__ cursor,
    int* __restrict__ perm)
{
    int bid = (int)blockIdx.x;
    if (bid < gblocks) {
        gemm_body0(x, W1, dinv, Y, N, bid, gblocks);
    } else if (bid < gblocks + eblocks) {
        int e = (bid - gblocks) * 256 + threadIdx.x;
        if (e < E) {
            int d = dst[e];
            csr[rng[d].x + rank[e]] = src[e];
        }
    } else {
        int i = (bid - gblocks - eblocks) * 256 + threadIdx.x;
        if (i < N) {
            int k = deg[i]; if (k > 255) k = 255;
            int slot = atomicAdd(&cursor[k], 1);
            perm[slot] = i;
        }
    }
}

// ======================= fp8 gather core (8 lanes/node) ====================
// Lane gl holds dwords 4gl..4gl+3 (features 16gl..16gl+15); one row = one
// uint4 load. csr for the next 8-chunk prefetched before the current rows'
// vmcnt wait. Degree-sorted callers -> near-uniform trip counts per wave.
__device__ __forceinline__ void gather_core16(
    const u32* __restrict__ Hl, const int* __restrict__ csr,
    int st, int en, float* acc)
{
    int j = st;
    if (j + 8 <= en) {
        int4 sa = *(const int4*)&csr[j];
        int4 sb = *(const int4*)&csr[j + 4];
        while (true) {
            int jn = j + 8;
            bool next8 = (jn + 8 <= en);
            int4 na, nb;
            if (next8) {                     // prefetch next chunk's indices
                na = *(const int4*)&csr[jn];
                nb = *(const int4*)&csr[jn + 4];
            }
            uint4 r0 = *(const uint4*)&Hl[(size_t)sa.x * 32];
            uint4 r1 = *(const uint4*)&Hl[(size_t)sa.y * 32];
            uint4 r2 = *(const uint4*)&Hl[(size_t)sa.z * 32];
            uint4 r3 = *(const uint4*)&Hl[(size_t)sa.w * 32];
            uint4 r4 = *(const uint4*)&Hl[(size_t)sb.x * 32];
            uint4 r5 = *(const uint4*)&Hl[(size_t)sb.y * 32];
            uint4 r6 = *(const uint4*)&Hl[(size_t)sb.z * 32];
            uint4 r7 = *(const uint4*)&Hl[(size_t)sb.w * 32];
            addrow16(acc, r0); addrow16(acc, r1);
            addrow16(acc, r2); addrow16(acc, r3);
            addrow16(acc, r4); addrow16(acc, r5);
            addrow16(acc, r6); addrow16(acc, r7);
            j = jn;
            if (!next8) break;
            sa = na; sb = nb;
        }
    }
    if (j < en) {   // exactly one 4-chunk
        int4 sa = *(const int4*)&csr[j];
        uint4 r0 = *(const uint4*)&Hl[(size_t)sa.x * 32];
        uint4 r1 = *(const uint4*)&Hl[(size_t)sa.y * 32];
        uint4 r2 = *(const uint4*)&Hl[(size_t)sa.z * 32];
        uint4 r3 = *(const uint4*)&Hl[(size_t)sa.w * 32];
        addrow16(acc, r0); addrow16(acc, r1);
        addrow16(acc, r2); addrow16(acc, r3);
    }
}

// ============== gather1 + GEMM2 fused (MFMA, 32 perm'd nodes/block) ========
// agg1[d] = (dinv[d]/16)*(sum B0[s] + B0[d]); h2 = relu(agg1+b1) @ W2;
// writes B1 = fp8(16*dinv*h2), node-major 32 u32/row (scattered by perm).
__global__ __launch_bounds__(256) void gather_gemm(
    const u32* __restrict__ H, u32* __restrict__ O,
    const int* __restrict__ csr, const int2* __restrict__ rng,
    const float* __restrict__ dinv, int N,
    const float* __restrict__ b1, const float* __restrict__ W2,
    const int* __restrict__ perm)
{
    __shared__ u32   Abuf[32][68];    // bf16 agg1 rows (68-dword pad)
    __shared__ float Dbuf[32][132];   // fp32 GEMM2 out rows

    const int t    = threadIdx.x;
    const int grp  = t >> 3;          // node-slot-in-block 0..31
    const int gl   = t & 7;
    const int idx  = blockIdx.x * 32 + grp;
    const bool valid = idx < N;

    const int lane = t & 63;
    const int wv   = t >> 6;          // wave id 0..3
    const int lrow = lane & 15;
    const int lhi  = lane >> 4;

    // ---- B fragments from global W2 (fp32 row-major 128x128) ----
    bf16x8 bfr[2][4];
    {
        const float* wp = W2 + (size_t)(lhi * 8) * DIM + wv * 32 + lrow;
        #pragma unroll
        for (int nt = 0; nt < 2; ++nt)
            #pragma unroll
            for (int kc = 0; kc < 4; ++kc) {
                const float* p = wp + (size_t)(kc * 32) * DIM + nt * 16;
                union { u32 u[4]; bf16x8 v; } tmp;
                #pragma unroll
                for (int e = 0; e < 4; ++e)
                    tmp.u[e] = pack_bf16x2(p[(size_t)(2 * e) * DIM],
                                           p[(size_t)(2 * e + 1) * DIM]);
                bfr[nt][kc] = tmp.v;
            }
    }

    // ---- phase 1: gather layer-1 neighborhood (fp8 B0, 8 lanes/node) ----
    float acc[16];
    #pragma unroll
    for (int i = 0; i < 16; ++i) acc[i] = 0.f;
    float dn = 0.f;
    int node = 0;
    if (valid) {
        node = perm[idx];
        const u32* Hl = H + gl * 4;
        int2 r = rng[node];
        gather_core16(Hl, csr, r.x, r.y, acc);
        addrow16(acc, *(const uint4*)&Hl[(size_t)node * 32]);   // self-loop
        dn = dinv[node] * 0.0625f;                              // descale /16
    }

    // relu(dn*acc + b1) -> bf16 -> Abuf (invalid rows never stored)
    {
        int f0 = gl * 16;
        float r[16];
        #pragma unroll
        for (int i = 0; i < 16; i += 4) {
            float4 bb = *(const float4*)&b1[f0 + i];
            r[i]     = fmaxf(fmaf(dn, acc[i],     bb.x), 0.f);
            r[i + 1] = fmaxf(fmaf(dn, acc[i + 1], bb.y), 0.f);
            r[i + 2] = fmaxf(fmaf(dn, acc[i + 2], bb.z), 0.f);
            r[i + 3] = fmaxf(fmaf(dn, acc[i + 3], bb.w), 0.f);
        }
        uint4 p0, p1;
        p0.x = pack_bf16x2(r[0],  r[1]);
        p0.y = pack_bf16x2(r[2],  r[3]);
        p0.z = pack_bf16x2(r[4],  r[5]);
        p0.w = pack_bf16x2(r[6],  r[7]);
        p1.x = pack_bf16x2(r[8],  r[9]);
        p1.y = pack_bf16x2(r[10], r[11]);
        p1.z = pack_bf16x2(r[12], r[13]);
        p1.w = pack_bf16x2(r[14], r[15]);
        *(uint4*)&Abuf[grp][gl * 8]     = p0;
        *(uint4*)&Abuf[grp][gl * 8 + 4] = p1;
    }
    __syncthreads();

    // ---- phase 2: MFMA GEMM2, two M=16 halves (16 MFMAs per wave) ----
    #pragma unroll
    for (int half = 0; half < 2; ++half) {
        f32x4 c0 = {0.f, 0.f, 0.f, 0.f};
        f32x4 c1 = {0.f, 0.f, 0.f, 0.f};
        #pragma unroll
        for (int kc = 0; kc < 4; ++kc) {
            bf16x8 afr = *(const bf16x8*)&Abuf[half * 16 + lrow][kc * 16 + lhi * 4];
            c0 = __builtin_amdgcn_mfma_f32_16x16x32_bf16(afr, bfr[0][kc], c0, 0, 0, 0);
            c1 = __builtin_amdgcn_mfma_f32_16x16x32_bf16(afr, bfr[1][kc], c1, 0, 0, 0);
        }
        #pragma unroll
        for (int r = 0; r < 4; ++r) {
            Dbuf[half * 16 + lhi * 4 + r][wv * 32 + lrow]      = c0[r];
            Dbuf[half * 16 + lhi * 4 + r][wv * 32 + 16 + lrow] = c1[r];
        }
    }
    __syncthreads();

    // ---- phase 3: 16x scale + fp8 pack + store (scattered by perm) ----
    if (valid) {
        float dnp = 16.f * dinv[node];
        float o[16];
        #pragma unroll
        for (int i = 0; i < 16; ++i) o[i] = Dbuf[grp][gl * 16 + i];
        uint4 ov;
        ov.x = enc_pair<true>(dnp * o[2],  dnp * o[3],
               enc_pair<false>(dnp * o[0],  dnp * o[1],  0u));
        ov.y = enc_pair<true>(dnp * o[6],  dnp * o[7],
               enc_pair<false>(dnp * o[4],  dnp * o[5],  0u));
        ov.z = enc_pair<true>(dnp * o[10], dnp * o[11],
               enc_pair<false>(dnp * o[8],  dnp * o[9],  0u));
        ov.w = enc_pair<true>(dnp * o[14], dnp * o[15],
               enc_pair<false>(dnp * o[12], dnp * o[13], 0u));
        *(uint4*)&O[(size_t)node * 32 + gl * 4] = ov;
    }
}

// ============== gather2 + pool fused (8 lanes/node, perm'd, 128-thr) =======
__global__ __launch_bounds__(128) void gather_pool(
    const u32* __restrict__ H,
    const int* __restrict__ csr, const int2* __restrict__ rng,
    const float* __restrict__ dinv, int N,
    const float* __restrict__ b2, const float* __restrict__ wlin,
    const int* __restrict__ batch, float* __restrict__ sums,
    float* __restrict__ cnt, const int* __restrict__ perm)
{
    const int grp = threadIdx.x >> 3;     // 0..15
    const int gl  = threadIdx.x & 7;
    const int idx = blockIdx.x * 16 + grp;
    if (idx >= N) return;
    const int node = perm[idx];

    float acc[16];
    #pragma unroll
    for (int i = 0; i < 16; ++i) acc[i] = 0.f;
    const u32* Hl = H + gl * 4;
    int2 r = rng[node];
    gather_core16(Hl, csr, r.x, r.y, acc);
    addrow16(acc, *(const uint4*)&Hl[(size_t)node * 32]);   // self-loop
    float dn = dinv[node] * 0.0625f;                        // descale /16

    int f0 = gl * 16;
    float v = 0.f;
    #pragma unroll
    for (int i = 0; i < 16; i += 4) {
        float4 bb = *(const float4*)&b2[f0 + i];
        float4 ww = *(const float4*)&wlin[f0 + i];
        v += fmaxf(fmaf(dn, acc[i],     bb.x), 0.f) * ww.x;
        v += fmaxf(fmaf(dn, acc[i + 1], bb.y), 0.f) * ww.y;
        v += fmaxf(fmaf(dn, acc[i + 2], bb.z), 0.f) * ww.z;
        v += fmaxf(fmaf(dn, acc[i + 3], bb.w), 0.f) * ww.w;
    }
    // 8-lane tree reduce (xor masks stay inside the group)
    v += __shfl_xor(v, 1, 64);
    v += __shfl_xor(v, 2, 64);
    v += __shfl_xor(v, 4, 64);
    if (gl == 0) {
        int g = batch[node];
        unsafeAtomicAdd(&sums[g], v);
        unsafeAtomicAdd(&cnt[g], 1.0f);
    }
}

__global__ void final_kernel(const float* __restrict__ sums,
                             const float* __restrict__ cnt,
                             const float* __restrict__ blin,
                             float* __restrict__ out, int G)
{
    int g = blockIdx.x * blockDim.x + threadIdx.x;
    if (g < G) out[g] = sums[g] / fmaxf(cnt[g], 1.0f) + blin[0];
}

// ======================= launch =======================

extern "C" void kernel_launch(void* const* d_in, const int* in_sizes, int n_in,
                              void* d_out, int out_size, void* d_ws, size_t ws_size,
                              hipStream_t stream)
{
    const float* x    = (const float*)d_in[0];
    const int*   src  = (const int*)d_in[1];
    const int*   dst  = (const int*)d_in[2];
    const int*   batch= (const int*)d_in[3];
    const float* W1   = (const float*)d_in[5];
    const float* b1   = (const float*)d_in[6];
    const float* W2   = (const float*)d_in[7];
    const float* b2   = (const float*)d_in[8];
    const float* wlin = (const float*)d_in[9];
    const float* blin = (const float*)d_in[10];
    float* out = (float*)d_out;

    const int N = in_sizes[0] / DIM;
    const int E = in_sizes[1];
    const int G = out_size;
    const size_t E_pad = (size_t)E + 4 * (size_t)N;   // per-bucket pad to x4

    // layout: B0((N+1)*32 u32 fp8), B1 likewise, dinv(N), sums(G), cnt(G),
    //         deg(N), rng(int2 N), rank(E), csr(E_pad), perm(N),
    //         hist(256), cursor(256), total
    // (dword count before rng is always even -> int2 is 8B-aligned)
    u32*   B0    = (u32*)d_ws;
    u32*   B1    = B0 + (size_t)(N + 1) * 32;
    float* dinv  = (float*)(B1 + (size_t)(N + 1) * 32);
    float* sums  = dinv + N;
    float* cnt   = sums + G;
    int*   deg_c = (int*)(cnt + G);
    int2*  rng   = (int2*)(deg_c + N);
    int*   rank  = (int*)(rng + N);
    int*   csr   = rank + E;
    int*   perm  = csr + E_pad;
    int*   hist  = perm + N;
    int*   cursor= hist + 256;
    int*   total = cursor + 256;
    size_t need_bytes = ((size_t)(total + 1) - (size_t)d_ws);
    if (ws_size < need_bytes) return;

    const int eblocks  = (E + 255) / 256;
    const int nblocks  = (N + 255) / 256;
    const int g4blocks = (N + 15) / 16;
    const int g1blocks = g4blocks < 1024 ? g4blocks : 1024;  // persistent gemm1
    const int g32blocks = (N + 31) / 32;

    (void)hipMemsetAsync(deg_c, 0, sizeof(int) * (size_t)N, stream);
    count_rank<<<eblocks, 256, 0, stream>>>(deg_c, dst, rank, total, E, hist);
    alloc_offsets<<<nblocks, 256, 0, stream>>>(deg_c, rng, dinv, total, csr, N,
                                               sums, cnt, G, B0, B1, hist);
    scan_kernel<<<1, 256, 0, stream>>>(hist, cursor);
    // gemm1 (MFMA, fp8 out) + CSR edge scatter + degree-sort perm scatter
    scatter_gemm1<<<g1blocks + eblocks + nblocks, 256, 0, stream>>>(
        x, W1, dinv, B0, N, g1blocks, src, dst, rank, rng, csr, E, eblocks,
        deg_c, cursor, perm);
    // layer 1 aggregation + layer 2 GEMM (fused, MFMA, degree-sorted)
    gather_gemm<<<g32blocks, 256, 0, stream>>>(B0, B1, csr, rng, dinv,
                                               N, b1, W2, perm);
    // layer 2 aggregation + pooling (fused, degree-sorted)
    gather_pool<<<g4blocks, 128, 0, stream>>>(B1, csr, rng, dinv, N,
                                              b2, wlin, batch, sums, cnt, perm);
    final_kernel<<<(G + 255) / 256, 256, 0, stream>>>(sums, cnt, blin, out, G);
}

// Round 9
// 235.717 us; speedup vs baseline: 1.7501x; 1.7501x over previous
//
#include <hip/hip_runtime.h>
#include <hip/hip_bf16.h>

#define DIM 128
typedef unsigned int u32;

typedef __attribute__((ext_vector_type(8))) short bf16x8;   // 8 bf16 (4 VGPRs)
typedef __attribute__((ext_vector_type(4))) float f32x4;    // MFMA accumulator
typedef __attribute__((ext_vector_type(2))) float f32x2;

// bf16x2 pack/unpack: low ushort = even feature, high = odd feature.
__device__ __forceinline__ u32 pack_bf16x2(float a, float b) {
    u32 ua = __float_as_uint(a), ub = __float_as_uint(b);
    ua = (ua + 0x7FFFu + ((ua >> 16) & 1u)) >> 16;        // RNE
    ub = (ub + 0x7FFFu + ((ub >> 16) & 1u)) >> 16;
    return ua | (ub << 16);
}
__device__ __forceinline__ float2 unpack_bf16x2(u32 h) {
    return make_float2(__uint_as_float(h << 16), __uint_as_float(h & 0xFFFF0000u));
}

// ======================= fp8 e4m3 helpers =======================
// Gather tables are fp8, pre-scaled by 16 (consumers descale via dinv/16).
// GATHER FLOOR LEDGER (do not re-litigate): ~62us/kernel, invariant to
// bytes (R6), lines/row (R6), occupancy 22-56% (R1/R6/R7), VMEM instr
// count (R7); node-reorder hurts via metadata randomization (R8);
// feature-slicing hurts via row-granularity collapse (R3).
#if __has_builtin(__builtin_amdgcn_cvt_pk_f32_fp8) && __has_builtin(__builtin_amdgcn_cvt_pk_fp8_f32)
#define FP8_HW 1
#endif

__device__ __forceinline__ void dec4(float* d, u32 w) {
#ifdef FP8_HW
    f32x2 a = __builtin_amdgcn_cvt_pk_f32_fp8((int)w, false);
    f32x2 b = __builtin_amdgcn_cvt_pk_f32_fp8((int)w, true);
    d[0] = a.x; d[1] = a.y; d[2] = b.x; d[3] = b.y;
#else
    #pragma unroll
    for (int i = 0; i < 4; ++i) {
        u32 v = (w >> (8 * i)) & 0xFFu;
        u32 s = v >> 7, e = (v >> 3) & 15u, m = v & 7u;
        float nv = __uint_as_float((s << 31) | ((e + 120u) << 23) | (m << 20));
        float sv = (s ? -1.f : 1.f) * (float)m * 0.001953125f;   // m * 2^-9
        d[i] = e ? nv : sv;
    }
#endif
}

#ifndef FP8_HW
__device__ __forceinline__ u32 enc_byte(float f) {   // software RNE e4m3
    u32 s = __float_as_uint(f) >> 31;
    float af = fminf(fabsf(f), 448.f);
    u32 b;
    if (af >= 0.015625f) {                       // normal (>= 2^-6)
        u32 m = __float_as_uint(af);
        m = m + 0x0007FFFFu + ((m >> 20) & 1u);  // RNE at bit 20
        u32 fe = (m >> 23) - 120u;
        if (fe > 15u) b = (15u << 3) | 6u;       // saturate to 448
        else          b = (fe << 3) | ((m >> 20) & 7u);
    } else {
        b = (u32)rintf(af * 512.f);              // subnormal quantum 2^-9
    }
    return b | (s << 7);
}
#endif

// HI must be a compile-time constant (ICE requirement of the builtin).
template<bool HI>
__device__ __forceinline__ u32 enc_pair(float a, float b, u32 old) {
#ifdef FP8_HW
    return (u32)__builtin_amdgcn_cvt_pk_fp8_f32(a, b, (int)old, HI);
#else
    u32 p = enc_byte(a) | (enc_byte(b) << 8);
    return HI ? ((old & 0x0000FFFFu) | (p << 16)) : ((old & 0xFFFF0000u) | p);
#endif
}

__device__ __forceinline__ void addrow8(float* acc, uint2 r) {
    float d[4];
    dec4(d, r.x);
    acc[0] += d[0]; acc[1] += d[1]; acc[2] += d[2]; acc[3] += d[3];
    dec4(d, r.y);
    acc[4] += d[0]; acc[5] += d[1]; acc[6] += d[2]; acc[7] += d[3];
}

__device__ __forceinline__ void addrow16(float* acc, uint4 r) {
    float d[4];
    dec4(d, r.x);
    acc[0]  += d[0]; acc[1]  += d[1]; acc[2]  += d[2]; acc[3]  += d[3];
    dec4(d, r.y);
    acc[4]  += d[0]; acc[5]  += d[1]; acc[6]  += d[2]; acc[7]  += d[3];
    dec4(d, r.z);
    acc[8]  += d[0]; acc[9]  += d[1]; acc[10] += d[2]; acc[11] += d[3];
    dec4(d, r.w);
    acc[12] += d[0]; acc[13] += d[1]; acc[14] += d[2]; acc[15] += d[3];
}

// ======================= count + rank =======================
__global__ void count_rank(int* __restrict__ deg, const int* __restrict__ dst,
                           int* __restrict__ rank, int* __restrict__ total, int E)
{
    int e = blockIdx.x * blockDim.x + threadIdx.x;
    if (e == 0) *total = 0;
    if (e < E) rank[e] = atomicAdd(&deg[dst[e]], 1);
}

// ======================= CSR offsets =======================
// Buckets padded to x4; pad slots point at the zero row (index N).
__global__ __launch_bounds__(256) void alloc_offsets(
    const int* __restrict__ deg, int* __restrict__ start, int* __restrict__ endp,
    float* __restrict__ dinv, int* __restrict__ total,
    int* __restrict__ csr, int N,
    float* __restrict__ sums, float* __restrict__ cnt, int G,
    u32* __restrict__ B0, u32* __restrict__ B1)
{
    int i = blockIdx.x * blockDim.x + threadIdx.x;
    int lane = threadIdx.x & 63;
    if (i < G) { sums[i] = 0.f; cnt[i] = 0.f; }
    if (i < 32) {                          // zero row N of both fp8 tables
        B0[(size_t)N * 32 + i] = 0u;
        B1[(size_t)N * 32 + i] = 0u;
    }
    int d  = (i < N) ? deg[i] : 0;
    int d4 = (d + 3) & ~3;
    int pre = d4;
    #pragma unroll
    for (int off = 1; off < 64; off <<= 1) {
        int v = __shfl_up(pre, off, 64);
        if (lane >= off) pre += v;
    }
    int waveTot = __shfl(pre, 63, 64);
    int base = 0;
    if (lane == 63) base = atomicAdd(total, waveTot);
    base = __shfl(base, 63, 64);
    if (i < N) {
        int st = base + pre - d4;
        start[i] = st;
        endp[i]  = st + d4;
        dinv[i]  = rsqrtf((float)(d + 1));   // +1 self-loop
        for (int p = d; p < d4; ++p)         // pads -> zero row
            csr[st + p] = N;
    }
}

// ======================= GEMM1 body (MFMA) =======================
// Y[node] = fp8(16 * dinv[node] * (X[node] @ W)), node-major 32 u32/row.
// 16x16x32 fragment maps (HW-verified): A: m=l&15, k=8*(l>>4)+e;
// B: n=l&15, k=8*(l>>4)+e; D: n=l&15, m=4*(l>>4)+r.
__device__ __forceinline__ void gemm_body0(
    const float* __restrict__ X, const float* __restrict__ W,
    const float* __restrict__ dinv, u32* __restrict__ Y, int N,
    int tile0, int tstride)
{
    __shared__ u32   Abuf[16][68];
    __shared__ float Dbuf[16][132];

    const int t    = threadIdx.x;
    const int grp  = t >> 4;
    const int gl   = t & 15;
    const int lane = t & 63;
    const int wv   = t >> 6;
    const int lrow = lane & 15;
    const int lhi  = lane >> 4;

    bf16x8 bfr[2][4];
    {
        const float* wp = W + (size_t)(lhi * 8) * DIM + wv * 32 + lrow;
        #pragma unroll
        for (int nt = 0; nt < 2; ++nt)
            #pragma unroll
            for (int kc = 0; kc < 4; ++kc) {
                const float* p = wp + (size_t)(kc * 32) * DIM + nt * 16;
                union { u32 u[4]; bf16x8 v; } tmp;
                #pragma unroll
                for (int e = 0; e < 4; ++e)
                    tmp.u[e] = pack_bf16x2(p[(size_t)(2 * e) * DIM],
                                           p[(size_t)(2 * e + 1) * DIM]);
                bfr[nt][kc] = tmp.v;
            }
    }

    const int ntiles = (N + 15) >> 4;
    for (int tile = tile0; tile < ntiles; tile += tstride) {
        const int node = tile * 16 + grp;
        const bool valid = node < N;

        float4 a0 = make_float4(0.f, 0.f, 0.f, 0.f);
        float4 a1 = make_float4(0.f, 0.f, 0.f, 0.f);
        if (valid) {
            a0 = *(const float4*)&X[(size_t)node * DIM + gl * 8];
            a1 = *(const float4*)&X[(size_t)node * DIM + gl * 8 + 4];
        }
        uint4 pk;
        pk.x = pack_bf16x2(a0.x, a0.y);
        pk.y = pack_bf16x2(a0.z, a0.w);
        pk.z = pack_bf16x2(a1.x, a1.y);
        pk.w = pack_bf16x2(a1.z, a1.w);
        *(uint4*)&Abuf[grp][gl * 4] = pk;
        __syncthreads();                                   // barrier A

        f32x4 c0 = {0.f, 0.f, 0.f, 0.f};
        f32x4 c1 = {0.f, 0.f, 0.f, 0.f};
        #pragma unroll
        for (int kc = 0; kc < 4; ++kc) {
            bf16x8 afr = *(const bf16x8*)&Abuf[lrow][kc * 16 + lhi * 4];
            c0 = __builtin_amdgcn_mfma_f32_16x16x32_bf16(afr, bfr[0][kc], c0, 0, 0, 0);
            c1 = __builtin_amdgcn_mfma_f32_16x16x32_bf16(afr, bfr[1][kc], c1, 0, 0, 0);
        }
        #pragma unroll
        for (int r = 0; r < 4; ++r) {
            Dbuf[lhi * 4 + r][wv * 32 + lrow]      = c0[r];
            Dbuf[lhi * 4 + r][wv * 32 + 16 + lrow] = c1[r];
        }
        __syncthreads();                                   // barrier B

        if (valid) {
            float dnp = 16.f * dinv[node];
            float4 o0 = *(const float4*)&Dbuf[grp][gl * 8];
            float4 o1 = *(const float4*)&Dbuf[grp][gl * 8 + 4];
            u32 lo = enc_pair<false>(dnp * o0.x, dnp * o0.y, 0u);
            lo     = enc_pair<true >(dnp * o0.z, dnp * o0.w, lo);
            u32 hi = enc_pair<false>(dnp * o1.x, dnp * o1.y, 0u);
            hi     = enc_pair<true >(dnp * o1.z, dnp * o1.w, hi);
            *(uint2*)&Y[(size_t)node * 32 + gl * 2] = make_uint2(lo, hi);
        }
    }
}

__global__ __launch_bounds__(256) void scatter_gemm1(
    const float* __restrict__ x, const float* __restrict__ W1,
    const float* __restrict__ dinv, u32* __restrict__ Y, int N, int gblocks,
    const int* __restrict__ src, const int* __restrict__ dst,
    const int* __restrict__ rank, const int* __restrict__ start,
    int* __restrict__ csr, int E)
{
    if ((int)blockIdx.x < gblocks) {
        gemm_body0(x, W1, dinv, Y, N, blockIdx.x, gblocks);
    } else {
        int e = ((int)blockIdx.x - gblocks) * 256 + threadIdx.x;
        if (e < E) {
            int d = dst[e];
            csr[start[d] + rank[e]] = src[e];
        }
    }
}

// ============== fp8 gather core, 16 lanes/node (best-measured, 62.5us) =====
// Lane gl holds dwords 2gl..2gl+1 (features 8gl..8gl+7); 4 nodes/wave.
__device__ __forceinline__ void gather_core8(
    const u32* __restrict__ Hl, const int* __restrict__ csr,
    int st, int en_pad, float* acc)
{
    int j = st;
    for (; j + 8 <= en_pad; j += 8) {
        int4 sa = *(const int4*)&csr[j];
        int4 sb = *(const int4*)&csr[j + 4];
        uint2 r0 = *(const uint2*)&Hl[(size_t)sa.x * 32];
        uint2 r1 = *(const uint2*)&Hl[(size_t)sa.y * 32];
        uint2 r2 = *(const uint2*)&Hl[(size_t)sa.z * 32];
        uint2 r3 = *(const uint2*)&Hl[(size_t)sa.w * 32];
        uint2 r4 = *(const uint2*)&Hl[(size_t)sb.x * 32];
        uint2 r5 = *(const uint2*)&Hl[(size_t)sb.y * 32];
        uint2 r6 = *(const uint2*)&Hl[(size_t)sb.z * 32];
        uint2 r7 = *(const uint2*)&Hl[(size_t)sb.w * 32];
        addrow8(acc, r0); addrow8(acc, r1); addrow8(acc, r2); addrow8(acc, r3);
        addrow8(acc, r4); addrow8(acc, r5); addrow8(acc, r6); addrow8(acc, r7);
    }
    if (j < en_pad) {   // exactly one 4-chunk
        int4 sa = *(const int4*)&csr[j];
        uint2 r0 = *(const uint2*)&Hl[(size_t)sa.x * 32];
        uint2 r1 = *(const uint2*)&Hl[(size_t)sa.y * 32];
        uint2 r2 = *(const uint2*)&Hl[(size_t)sa.z * 32];
        uint2 r3 = *(const uint2*)&Hl[(size_t)sa.w * 32];
        addrow8(acc, r0); addrow8(acc, r1); addrow8(acc, r2); addrow8(acc, r3);
    }
}

// ============== fp8 gather core, 8 lanes/node (used by gather_gemm) ========
// Lane gl holds dwords 4gl..4gl+3 (features 16gl..16gl+15); csr prefetch.
__device__ __forceinline__ void gather_core16(
    const u32* __restrict__ Hl, const int* __restrict__ csr,
    int st, int en, float* acc)
{
    int j = st;
    if (j + 8 <= en) {
        int4 sa = *(const int4*)&csr[j];
        int4 sb = *(const int4*)&csr[j + 4];
        while (true) {
            int jn = j + 8;
            bool next8 = (jn + 8 <= en);
            int4 na, nb;
            if (next8) {                     // prefetch next chunk's indices
                na = *(const int4*)&csr[jn];
                nb = *(const int4*)&csr[jn + 4];
            }
            uint4 r0 = *(const uint4*)&Hl[(size_t)sa.x * 32];
            uint4 r1 = *(const uint4*)&Hl[(size_t)sa.y * 32];
            uint4 r2 = *(const uint4*)&Hl[(size_t)sa.z * 32];
            uint4 r3 = *(const uint4*)&Hl[(size_t)sa.w * 32];
            uint4 r4 = *(const uint4*)&Hl[(size_t)sb.x * 32];
            uint4 r5 = *(const uint4*)&Hl[(size_t)sb.y * 32];
            uint4 r6 = *(const uint4*)&Hl[(size_t)sb.z * 32];
            uint4 r7 = *(const uint4*)&Hl[(size_t)sb.w * 32];
            addrow16(acc, r0); addrow16(acc, r1);
            addrow16(acc, r2); addrow16(acc, r3);
            addrow16(acc, r4); addrow16(acc, r5);
            addrow16(acc, r6); addrow16(acc, r7);
            j = jn;
            if (!next8) break;
            sa = na; sb = nb;
        }
    }
    if (j < en) {   // exactly one 4-chunk
        int4 sa = *(const int4*)&csr[j];
        uint4 r0 = *(const uint4*)&Hl[(size_t)sa.x * 32];
        uint4 r1 = *(const uint4*)&Hl[(size_t)sa.y * 32];
        uint4 r2 = *(const uint4*)&Hl[(size_t)sa.z * 32];
        uint4 r3 = *(const uint4*)&Hl[(size_t)sa.w * 32];
        addrow16(acc, r0); addrow16(acc, r1);
        addrow16(acc, r2); addrow16(acc, r3);
    }
}

// ============== gather1 + GEMM2 fused (MFMA, 32 nodes/block) ==============
// agg1[d] = (dinv[d]/16)*(sum B0[s] + B0[d]); h2 = relu(agg1+b1) @ W2;
// writes B1 = fp8(16*dinv*h2), node-major 32 u32/row.
// Block = 32 nodes = two M=16 MFMA tiles sharing the same W2 fragments.
__global__ __launch_bounds__(256) void gather_gemm(
    const u32* __restrict__ H, u32* __restrict__ O,
    const int* __restrict__ csr, const int* __restrict__ start,
    const int* __restrict__ endp, const float* __restrict__ dinv, int N,
    const float* __restrict__ b1, const float* __restrict__ W2)
{
    __shared__ u32   Abuf[32][68];    // bf16 agg1 rows (68-dword pad)
    __shared__ float Dbuf[32][132];   // fp32 GEMM2 out rows

    const int t    = threadIdx.x;
    const int grp  = t >> 3;          // node-in-block 0..31
    const int gl   = t & 7;
    const int node = blockIdx.x * 32 + grp;
    const bool valid = node < N;

    const int lane = t & 63;
    const int wv   = t >> 6;          // wave id 0..3
    const int lrow = lane & 15;
    const int lhi  = lane >> 4;

    // ---- B fragments from global W2 (fp32 row-major 128x128) ----
    bf16x8 bfr[2][4];
    {
        const float* wp = W2 + (size_t)(lhi * 8) * DIM + wv * 32 + lrow;
        #pragma unroll
        for (int nt = 0; nt < 2; ++nt)
            #pragma unroll
            for (int kc = 0; kc < 4; ++kc) {
                const float* p = wp + (size_t)(kc * 32) * DIM + nt * 16;
                union { u32 u[4]; bf16x8 v; } tmp;
                #pragma unroll
                for (int e = 0; e < 4; ++e)
                    tmp.u[e] = pack_bf16x2(p[(size_t)(2 * e) * DIM],
                                           p[(size_t)(2 * e + 1) * DIM]);
                bfr[nt][kc] = tmp.v;
            }
    }

    // ---- phase 1: gather layer-1 neighborhood (fp8 B0, 8 lanes/node) ----
    float acc[16];
    #pragma unroll
    for (int i = 0; i < 16; ++i) acc[i] = 0.f;
    float dn = 0.f;
    if (valid) {
        const u32* Hl = H + gl * 4;
        gather_core16(Hl, csr, start[node], endp[node], acc);
        addrow16(acc, *(const uint4*)&Hl[(size_t)node * 32]);   // self-loop
        dn = dinv[node] * 0.0625f;                              // descale /16
    }

    // relu(dn*acc + b1) -> bf16 -> Abuf (invalid rows never stored)
    {
        int f0 = gl * 16;
        float r[16];
        #pragma unroll
        for (int i = 0; i < 16; i += 4) {
            float4 bb = *(const float4*)&b1[f0 + i];
            r[i]     = fmaxf(fmaf(dn, acc[i],     bb.x), 0.f);
            r[i + 1] = fmaxf(fmaf(dn, acc[i + 1], bb.y), 0.f);
            r[i + 2] = fmaxf(fmaf(dn, acc[i + 2], bb.z), 0.f);
            r[i + 3] = fmaxf(fmaf(dn, acc[i + 3], bb.w), 0.f);
        }
        uint4 p0, p1;
        p0.x = pack_bf16x2(r[0],  r[1]);
        p0.y = pack_bf16x2(r[2],  r[3]);
        p0.z = pack_bf16x2(r[4],  r[5]);
        p0.w = pack_bf16x2(r[6],  r[7]);
        p1.x = pack_bf16x2(r[8],  r[9]);
        p1.y = pack_bf16x2(r[10], r[11]);
        p1.z = pack_bf16x2(r[12], r[13]);
        p1.w = pack_bf16x2(r[14], r[15]);
        *(uint4*)&Abuf[grp][gl * 8]     = p0;
        *(uint4*)&Abuf[grp][gl * 8 + 4] = p1;
    }
    __syncthreads();

    // ---- phase 2: MFMA GEMM2, two M=16 halves (16 MFMAs per wave) ----
    #pragma unroll
    for (int half = 0; half < 2; ++half) {
        f32x4 c0 = {0.f, 0.f, 0.f, 0.f};
        f32x4 c1 = {0.f, 0.f, 0.f, 0.f};
        #pragma unroll
        for (int kc = 0; kc < 4; ++kc) {
            bf16x8 afr = *(const bf16x8*)&Abuf[half * 16 + lrow][kc * 16 + lhi * 4];
            c0 = __builtin_amdgcn_mfma_f32_16x16x32_bf16(afr, bfr[0][kc], c0, 0, 0, 0);
            c1 = __builtin_amdgcn_mfma_f32_16x16x32_bf16(afr, bfr[1][kc], c1, 0, 0, 0);
        }
        #pragma unroll
        for (int r = 0; r < 4; ++r) {
            Dbuf[half * 16 + lhi * 4 + r][wv * 32 + lrow]      = c0[r];
            Dbuf[half * 16 + lhi * 4 + r][wv * 32 + 16 + lrow] = c1[r];
        }
    }
    __syncthreads();

    // ---- phase 3: 16x scale + fp8 pack + coalesced store ----
    if (valid) {
        float dnp = 16.f * dinv[node];
        float o[16];
        #pragma unroll
        for (int i = 0; i < 16; ++i) o[i] = Dbuf[grp][gl * 16 + i];
        uint4 ov;
        ov.x = enc_pair<true>(dnp * o[2],  dnp * o[3],
               enc_pair<false>(dnp * o[0],  dnp * o[1],  0u));
        ov.y = enc_pair<true>(dnp * o[6],  dnp * o[7],
               enc_pair<false>(dnp * o[4],  dnp * o[5],  0u));
        ov.z = enc_pair<true>(dnp * o[10], dnp * o[11],
               enc_pair<false>(dnp * o[8],  dnp * o[9],  0u));
        ov.w = enc_pair<true>(dnp * o[14], dnp * o[15],
               enc_pair<false>(dnp * o[12], dnp * o[13], 0u));
        *(uint4*)&O[(size_t)node * 32 + gl * 4] = ov;
    }
}

// ============== gather2 + pool fused (16 lanes/node, early return) =========
__global__ __launch_bounds__(256) void gather_pool(
    const u32* __restrict__ H,
    const int* __restrict__ csr, const int* __restrict__ start,
    const int* __restrict__ endp, const float* __restrict__ dinv, int N,
    const float* __restrict__ b2, const float* __restrict__ wlin,
    const int* __restrict__ batch, float* __restrict__ sums, float* __restrict__ cnt)
{
    const int grp  = threadIdx.x >> 4;
    const int gl   = threadIdx.x & 15;
    const int node = blockIdx.x * 16 + grp;
    if (node >= N) return;

    float acc[8] = {0.f,0.f,0.f,0.f,0.f,0.f,0.f,0.f};
    const u32* Hl = H + gl * 2;
    gather_core8(Hl, csr, start[node], endp[node], acc);
    addrow8(acc, *(const uint2*)&Hl[(size_t)node * 32]);   // self-loop
    float dn = dinv[node] * 0.0625f;                       // descale /16

    int f0 = gl * 8;
    float v = 0.f;
    #pragma unroll
    for (int i = 0; i < 8; ++i)
        v += fmaxf(fmaf(dn, acc[i], b2[f0 + i]), 0.f) * wlin[f0 + i];
    #pragma unroll
    for (int m = 1; m <= 8; m <<= 1) v += __shfl_xor(v, m, 64);
    if (gl == 0) {
        int g = batch[node];
        unsafeAtomicAdd(&sums[g], v);
        unsafeAtomicAdd(&cnt[g], 1.0f);
    }
}

__global__ void final_kernel(const float* __restrict__ sums,
                             const float* __restrict__ cnt,
                             const float* __restrict__ blin,
                             float* __restrict__ out, int G)
{
    int g = blockIdx.x * blockDim.x + threadIdx.x;
    if (g < G) out[g] = sums[g] / fmaxf(cnt[g], 1.0f) + blin[0];
}

// ======================= launch =======================

extern "C" void kernel_launch(void* const* d_in, const int* in_sizes, int n_in,
                              void* d_out, int out_size, void* d_ws, size_t ws_size,
                              hipStream_t stream)
{
    const float* x    = (const float*)d_in[0];
    const int*   src  = (const int*)d_in[1];
    const int*   dst  = (const int*)d_in[2];
    const int*   batch= (const int*)d_in[3];
    const float* W1   = (const float*)d_in[5];
    const float* b1   = (const float*)d_in[6];
    const float* W2   = (const float*)d_in[7];
    const float* b2   = (const float*)d_in[8];
    const float* wlin = (const float*)d_in[9];
    const float* blin = (const float*)d_in[10];
    float* out = (float*)d_out;

    const int N = in_sizes[0] / DIM;
    const int E = in_sizes[1];
    const int G = out_size;
    const size_t E_pad = (size_t)E + 4 * (size_t)N;   // per-bucket pad to x4

    // layout: B0((N+1)*32 u32 fp8, row N = zero row), B1 likewise, dinv(N),
    //         sums(G), cnt(G), deg(N), start(N), endp(N), rank(E),
    //         csr(int E_pad), total
    u32*   B0    = (u32*)d_ws;
    u32*   B1    = B0 + (size_t)(N + 1) * 32;
    float* dinv  = (float*)(B1 + (size_t)(N + 1) * 32);
    float* sums  = dinv + N;
    float* cnt   = sums + G;
    int*   deg_c = (int*)(cnt + G);
    int*   start = deg_c + N;
    int*   endp  = start + N;
    int*   rank  = endp + N;
    int*   csr   = rank + E;
    int*   total = csr + E_pad;
    size_t need_bytes = ((size_t)(total + 1) - (size_t)d_ws);
    if (ws_size < need_bytes) return;

    const int eblocks  = (E + 255) / 256;
    const int g4blocks = (N + 15) / 16;
    const int g1blocks = g4blocks < 1024 ? g4blocks : 1024;  // persistent gemm1
    const int g32blocks = (N + 31) / 32;

    (void)hipMemsetAsync(deg_c, 0, sizeof(int) * (size_t)N, stream);
    count_rank<<<eblocks, 256, 0, stream>>>(deg_c, dst, rank, total, E);
    alloc_offsets<<<(N + 255) / 256, 256, 0, stream>>>(deg_c, start, endp,
                                                       dinv, total, csr, N,
                                                       sums, cnt, G, B0, B1);
    // gemm1 (MFMA, fp8 output) fused with atomic-free edge scatter
    scatter_gemm1<<<g1blocks + eblocks, 256, 0, stream>>>(x, W1, dinv, B0, N,
                                                          g1blocks, src, dst,
                                                          rank, start, csr, E);
    // layer 1 aggregation + layer 2 GEMM (fused, MFMA, 32 nodes/block)
    gather_gemm<<<g32blocks, 256, 0, stream>>>(B0, B1, csr, start, endp, dinv,
                                               N, b1, W2);
    // layer 2 aggregation + pooling (fused, 16 lanes/node)
    gather_pool<<<g4blocks, 256, 0, stream>>>(B1, csr, start, endp, dinv, N,
                                              b2, wlin, batch, sums, cnt);
    final_kernel<<<(G + 255) / 256, 256, 0, stream>>>(sums, cnt, blin, out, G);
}